// Round 9
// baseline (484.348 us; speedup 1.0000x reference)
//
#include <hip/hip_runtime.h>

#define LEAKY_SLOPE 0.01f
#define CBSH 7
#define CBSZ 128          // nodes per coarse bucket
#define CHUNK 4096        // edges per scat1 block

__device__ __forceinline__ unsigned short f2bf(float f) {
    unsigned int u = __builtin_bit_cast(unsigned int, f);
    u = (u + 0x7FFFu + ((u >> 16) & 1u)) >> 16;   // round-to-nearest-even
    return (unsigned short)u;
}
__device__ __forceinline__ float ulof(unsigned u) {
    return __builtin_bit_cast(float, u << 16);
}
__device__ __forceinline__ float uhif(unsigned u) {
    return __builtin_bit_cast(float, u & 0xFFFF0000u);
}

// ---------------------------------------------------------------------------
// coarse histogram by dst>>7 (LDS-privatized)
// ---------------------------------------------------------------------------
__global__ __launch_bounds__(256) void chist_kernel(const int* __restrict__ dst,
                                                    int* __restrict__ cbin, int E, int ncb) {
    __shared__ int bins[1024];
    for (int i = threadIdx.x; i < 1024; i += 256) bins[i] = 0;
    __syncthreads();
    int stride = gridDim.x * blockDim.x;
    for (int e = blockIdx.x * blockDim.x + threadIdx.x; e < E; e += stride)
        atomicAdd(&bins[dst[e] >> CBSH], 1);
    __syncthreads();
    for (int i = threadIdx.x; i < ncb; i += 256) {
        int v = bins[i];
        if (v) atomicAdd(&cbin[i], v);
    }
}

// single-block scan of coarse bins -> offsets + 64B-strided cursor init
__global__ __launch_bounds__(256) void cscan_kernel(const int* __restrict__ cbin,
                                                    int* __restrict__ cboff,
                                                    int* __restrict__ ccur16, int ncb) {
    __shared__ int s[256];
    __shared__ int carry;
    int t = threadIdx.x;
    if (t == 0) carry = 0;
    __syncthreads();
    for (int base = 0; base < ncb; base += 256) {
        int v = (base + t < ncb) ? cbin[base + t] : 0;
        s[t] = v;
        __syncthreads();
        for (int off = 1; off < 256; off <<= 1) {
            int u = (t >= off) ? s[t - off] : 0;
            __syncthreads();
            s[t] += u;
            __syncthreads();
        }
        int excl = carry + s[t] - v;
        if (base + t < ncb) { cboff[base + t] = excl; ccur16[(size_t)(base + t) * 16] = excl; }
        __syncthreads();
        if (t == 0) carry += s[255];
        __syncthreads();
    }
    if (t == 0) cboff[ncb] = carry;
}

// ---------------------------------------------------------------------------
// blocked level-1 scatter: per-block LDS histogram -> one global atomic per
// (block,bucket) chunk reservation -> LDS-cursor scatter.
// ---------------------------------------------------------------------------
__global__ __launch_bounds__(256) void scat1_kernel(const int* __restrict__ src,
                                                    const int* __restrict__ dst,
                                                    int* __restrict__ ccur16,
                                                    unsigned* __restrict__ pairs, int E) {
    __shared__ int bins[1024];
    __shared__ int base[1024];
    int t = threadIdx.x;
    for (int i = t; i < 1024; i += 256) bins[i] = 0;
    __syncthreads();
    int e0 = blockIdx.x * CHUNK;
    int m = min(CHUNK, E - e0);
    for (int i = t; i < m; i += 256)
        atomicAdd(&bins[dst[e0 + i] >> CBSH], 1);
    __syncthreads();
    for (int i = t; i < 1024; i += 256) {
        int c = bins[i];
        base[i] = c ? atomicAdd(&ccur16[(size_t)i * 16], c) : 0;
        bins[i] = 0;   // reuse as local cursor
    }
    __syncthreads();
    for (int i = t; i < m; i += 256) {
        int d = dst[e0 + i];
        int b = d >> CBSH;
        int off = atomicAdd(&bins[b], 1);
        pairs[base[b] + off] = (unsigned)src[e0 + i] | ((unsigned)(d & (CBSZ - 1)) << 17);
    }
}

// per-bucket degree (LDS histogram) -> dis + padded degree (multiple of 16)
__global__ __launch_bounds__(256) void degbuild_kernel(const unsigned* __restrict__ pairs,
                                                       const int* __restrict__ cboff,
                                                       float* __restrict__ dis,
                                                       int* __restrict__ dpad, int n) {
    __shared__ int cnt[CBSZ];
    int t = threadIdx.x;
    int b = blockIdx.x;
    if (t < CBSZ) cnt[t] = 0;
    __syncthreads();
    int e1 = cboff[b + 1];
    for (int e = cboff[b] + t; e < e1; e += 256)
        atomicAdd(&cnt[pairs[e] >> 17], 1);
    __syncthreads();
    if (t < CBSZ) {
        int node = b * CBSZ + t;
        if (node < n) {
            int d = cnt[t];
            dis[node] = rsqrtf((float)d + 1.0f);
            dpad[node] = (d + 15) & ~15;
        }
    }
}

// ---------------------------------------------------------------------------
// scan chain over padded degrees -> rp (padded CSR offsets)
// ---------------------------------------------------------------------------
__global__ void scan_block_sums(const int* __restrict__ deg, int* __restrict__ bsum, int n) {
    __shared__ int sdata[256];
    int i = blockIdx.x * 256 + threadIdx.x;
    int t = threadIdx.x;
    sdata[t] = (i < n) ? deg[i] : 0;
    __syncthreads();
    for (int s = 128; s > 0; s >>= 1) {
        if (t < s) sdata[t] += sdata[t + s];
        __syncthreads();
    }
    if (t == 0) bsum[blockIdx.x] = sdata[0];
}

__global__ void scan_partials(int* __restrict__ bsum, int nb, int* __restrict__ rp_end) {
    __shared__ int s[512];
    int t = threadIdx.x;
    int orig = (t < nb) ? bsum[t] : 0;
    s[t] = orig;
    __syncthreads();
    for (int off = 1; off < 512; off <<= 1) {
        int v = (t >= off) ? s[t - off] : 0;
        __syncthreads();
        s[t] += v;
        __syncthreads();
    }
    if (t < nb) bsum[t] = s[t] - orig;   // exclusive
    if (t == 0) rp_end[0] = s[511];      // total padded edges
}

__global__ void scan_final(const int* __restrict__ deg, const int* __restrict__ bsum,
                           int* __restrict__ rp, int n) {
    __shared__ int s[256];
    int i = blockIdx.x * 256 + threadIdx.x;
    int t = threadIdx.x;
    int orig = (i < n) ? deg[i] : 0;
    s[t] = orig;
    __syncthreads();
    for (int off = 1; off < 256; off <<= 1) {
        int v = (t >= off) ? s[t - off] : 0;
        __syncthreads();
        s[t] += v;
        __syncthreads();
    }
    if (i < n) rp[i] = s[t] - orig + bsum[blockIdx.x];
}

// level-2 scatter + pad fill: place edges at exact padded CSR positions via
// LDS cursors, then fill each node's pad slots (<=15) with dummy index n.
__global__ __launch_bounds__(256) void scat2_kernel(const unsigned* __restrict__ pairs,
                                                    const int* __restrict__ cboff,
                                                    const int* __restrict__ rp,
                                                    int* __restrict__ ssrc, int n) {
    __shared__ int lrp[CBSZ];
    __shared__ int lcnt[CBSZ];
    int t = threadIdx.x;
    int b = blockIdx.x;
    if (t < CBSZ) {
        int node = b * CBSZ + t;
        lrp[t] = (node < n) ? rp[node] : 0;
        lcnt[t] = 0;
    }
    __syncthreads();
    int e1 = cboff[b + 1];
    for (int e = cboff[b] + t; e < e1; e += 256) {
        unsigned p = pairs[e];
        int dl = p >> 17;
        int off = atomicAdd(&lcnt[dl], 1);
        ssrc[lrp[dl] + off] = (int)(p & 0x1FFFFu);
    }
    __syncthreads();
    if (t < CBSZ) {
        int node = b * CBSZ + t;
        if (node < n) {
            int c0 = lcnt[t];
            int cpad = (c0 + 15) & ~15;
            int base = lrp[t];
            for (int i = c0; i < cpad; ++i) ssrc[base + i] = n;
        }
    }
}

// zero the dummy row (node n) in both sliced feature buffers (4 slices x 32B)
__global__ void zerorow_kernel(unsigned* __restrict__ A, unsigned* __restrict__ B,
                               int n, int Np1) {
    int t = threadIdx.x;   // 64 threads
    int buf = t >> 5;
    int u = t & 31;
    int s = u >> 3, w = u & 7;
    unsigned* p = buf ? B : A;
    p[((size_t)s * Np1 + n) * 8 + w] = 0;
}

// ---------------------------------------------------------------------------
// gemm1s: Hs1[s][row][16] = bf16((X[N,128] @ W1[128,64]) * dis) sliced layout
// ---------------------------------------------------------------------------
__global__ __launch_bounds__(256) void gemm1s_kernel(const float* __restrict__ X,
                                                     const float* __restrict__ W,
                                                     const float* __restrict__ dis,
                                                     unsigned short* __restrict__ Hh,
                                                     int N, int Np1) {
    __shared__ float Xs[16 * 128];
    int tid = threadIdx.x;
    int row0 = blockIdx.x * 16;
    for (int i = tid * 4; i < 16 * 128; i += 256 * 4)
        *(float4*)&Xs[i] = *(const float4*)&X[(size_t)row0 * 128 + i];
    __syncthreads();

    int c = tid & 63;
    int g = tid >> 6;
    float acc[4] = {0.f, 0.f, 0.f, 0.f};
    for (int kk = 0; kk < 128; kk += 16) {
        float w[16];
#pragma unroll
        for (int k = 0; k < 16; ++k) w[k] = W[(kk + k) * 64 + c];
#pragma unroll
        for (int r = 0; r < 4; ++r) {
            int row = g + r * 4;
#pragma unroll
            for (int k4 = 0; k4 < 16; k4 += 4) {
                float4 x4 = *(float4*)&Xs[row * 128 + kk + k4];
                acc[r] += x4.x * w[k4] + x4.y * w[k4 + 1] + x4.z * w[k4 + 2] + x4.w * w[k4 + 3];
            }
        }
    }
    int s = c >> 4, cc = c & 15;
#pragma unroll
    for (int r = 0; r < 4; ++r) {
        int row = row0 + g + r * 4;
        Hh[((size_t)s * Np1 + row) * 16 + cc] = f2bf(acc[r] * dis[row]);
    }
}

// ---------------------------------------------------------------------------
// Sliced gather: one 16-channel slice (3.2MB, L2-resident) per launch.
// Wave = 8 groups x 8 lanes; per 16 edges: 1 int2 index load + 2 row loads
// (32B/group). Cross-group reduce via shfl_xor. MODE:
//   0: h1 = leaky(acc*d + bias)            -> f32 std [node][64]
//   1: h2s = leaky(acc*d + bias)*d         -> bf16 sliced
//   2: g = acc*d                           -> f32 std [node][64]
// ---------------------------------------------------------------------------
template <int MODE>
__global__ __launch_bounds__(256) void sgather_kernel(
    const unsigned* __restrict__ Hsrc, const int* __restrict__ rp,
    const int* __restrict__ ssrc, const float* __restrict__ dis,
    const float* __restrict__ bias, void* __restrict__ outp,
    int n, int Np1, int s) {
    int lane = threadIdx.x & 63;
    int g = lane >> 3, p = lane & 7;
    const unsigned* Hs = Hsrc + (size_t)s * Np1 * 8;

    float2 bv = make_float2(0.f, 0.f);
    if (MODE < 2) bv = *(const float2*)&bias[s * 16 + 2 * p];

    int wid = (int)((blockIdx.x * blockDim.x + threadIdx.x) >> 6);
    int nwaves = (int)((gridDim.x * blockDim.x) >> 6);
    for (; wid < n; wid += nwaves) {
        int e0 = rp[wid];
        int e1 = rp[wid + 1];
        const int* sp = ssrc + e0;
        int cnt = e1 - e0;
        float a0 = 0.f, a1 = 0.f;
        for (int i = 0; i < cnt; i += 16) {
            int2 s2 = *(const int2*)&sp[i + 2 * g];
            unsigned q0 = Hs[(size_t)s2.x * 8 + p];
            unsigned q1 = Hs[(size_t)s2.y * 8 + p];
            a0 += ulof(q0) + ulof(q1);
            a1 += uhif(q0) + uhif(q1);
        }
        a0 += __shfl_xor(a0, 8); a0 += __shfl_xor(a0, 16); a0 += __shfl_xor(a0, 32);
        a1 += __shfl_xor(a1, 8); a1 += __shfl_xor(a1, 16); a1 += __shfl_xor(a1, 32);
        unsigned qs = Hs[(size_t)wid * 8 + p];
        a0 += ulof(qs);
        a1 += uhif(qs);
        float d = dis[wid];
        if (MODE == 0) {
            float h0 = fmaf(a0, d, bv.x);
            float h1 = fmaf(a1, d, bv.y);
            h0 = h0 > 0.f ? h0 : LEAKY_SLOPE * h0;
            h1 = h1 > 0.f ? h1 : LEAKY_SLOPE * h1;
            if (g == 0)
                *(float2*)&((float*)outp)[(size_t)wid * 64 + s * 16 + 2 * p] = make_float2(h0, h1);
        } else if (MODE == 1) {
            float h0 = fmaf(a0, d, bv.x);
            float h1 = fmaf(a1, d, bv.y);
            h0 = (h0 > 0.f ? h0 : LEAKY_SLOPE * h0) * d;
            h1 = (h1 > 0.f ? h1 : LEAKY_SLOPE * h1) * d;
            unsigned u = (unsigned)f2bf(h0) | ((unsigned)f2bf(h1) << 16);
            if (g == 0)
                ((unsigned*)outp)[((size_t)s * Np1 + wid) * 8 + p] = u;
        } else {
            float g0 = a0 * d;
            float g1 = a1 * d;
            if (g == 0)
                *(float2*)&((float*)outp)[(size_t)wid * 64 + s * 16 + 2 * p] = make_float2(g0, g1);
        }
    }
}

// ---------------------------------------------------------------------------
// gemmA: Hs2 = bf16((h1[N,64] @ W2[64,64]) * dis) -> sliced layout
// ---------------------------------------------------------------------------
__global__ __launch_bounds__(256) void gemmA_kernel(const float* __restrict__ h1,
                                                    const float* __restrict__ W2,
                                                    const float* __restrict__ dis,
                                                    unsigned short* __restrict__ Hh,
                                                    int N, int Np1) {
    __shared__ float Xs[16 * 64];
    int tid = threadIdx.x;
    int row0 = blockIdx.x * 16;
    *(float4*)&Xs[tid * 4] = *(const float4*)&h1[(size_t)row0 * 64 + tid * 4];
    __syncthreads();

    int c = tid & 63;
    int g = tid >> 6;
    float acc[4] = {0.f, 0.f, 0.f, 0.f};
    for (int kk = 0; kk < 64; kk += 16) {
        float w[16];
#pragma unroll
        for (int k = 0; k < 16; ++k) w[k] = W2[(kk + k) * 64 + c];
#pragma unroll
        for (int r = 0; r < 4; ++r) {
            int row = g + r * 4;
#pragma unroll
            for (int k4 = 0; k4 < 16; k4 += 4) {
                float4 x4 = *(float4*)&Xs[row * 64 + kk + k4];
                acc[r] += x4.x * w[k4] + x4.y * w[k4 + 1] + x4.z * w[k4 + 2] + x4.w * w[k4 + 3];
            }
        }
    }
    int s = c >> 4, cc = c & 15;
#pragma unroll
    for (int r = 0; r < 4; ++r) {
        int row = row0 + g + r * 4;
        Hh[((size_t)s * Np1 + row) * 16 + cc] = f2bf(acc[r] * dis[row]);
    }
}

// ---------------------------------------------------------------------------
// gemmC: mu = g@Wmu + bmu ; ls = g@Wls + bls  (g f32 std layout)
// ---------------------------------------------------------------------------
__global__ __launch_bounds__(256) void gemmC_kernel(const float* __restrict__ gbuf,
                                                    const float* __restrict__ Wmu,
                                                    const float* __restrict__ bmu,
                                                    const float* __restrict__ Wls,
                                                    const float* __restrict__ bls,
                                                    float* __restrict__ mu,
                                                    float* __restrict__ ls, int N) {
    __shared__ float Xs[16 * 64];
    int tid = threadIdx.x;
    int row0 = blockIdx.x * 16;
    *(float4*)&Xs[tid * 4] = *(const float4*)&gbuf[(size_t)row0 * 64 + tid * 4];
    __syncthreads();

    int c = tid & 63;
    int g = tid >> 6;
    int half = c >> 5;
    int cc = c & 31;
    const float* Wp = half ? Wls : Wmu;
    float bias = half ? bls[cc] : bmu[cc];
    float* outp = half ? ls : mu;

    float acc[4] = {0.f, 0.f, 0.f, 0.f};
    for (int kk = 0; kk < 64; kk += 16) {
        float w[16];
#pragma unroll
        for (int k = 0; k < 16; ++k) w[k] = Wp[(kk + k) * 32 + cc];
#pragma unroll
        for (int r = 0; r < 4; ++r) {
            int row = g + r * 4;
#pragma unroll
            for (int k4 = 0; k4 < 16; k4 += 4) {
                float4 x4 = *(float4*)&Xs[row * 64 + kk + k4];
                acc[r] += x4.x * w[k4] + x4.y * w[k4 + 1] + x4.z * w[k4 + 2] + x4.w * w[k4 + 3];
            }
        }
    }
#pragma unroll
    for (int r = 0; r < 4; ++r) {
        int row = row0 + g + r * 4;
        outp[(size_t)row * 32 + cc] = acc[r] + bias;
    }
}

// ---------------------------------------------------------------------------
extern "C" void kernel_launch(void* const* d_in, const int* in_sizes, int n_in,
                              void* d_out, int out_size, void* d_ws, size_t ws_size,
                              hipStream_t stream) {
    const float* x   = (const float*)d_in[0];
    const int*   ei  = (const int*)d_in[1];
    const float* W1  = (const float*)d_in[2];
    const float* b1  = (const float*)d_in[3];
    const float* W2  = (const float*)d_in[4];
    const float* b2  = (const float*)d_in[5];
    const float* Wmu = (const float*)d_in[6];
    const float* bmu = (const float*)d_in[7];
    const float* Wls = (const float*)d_in[8];
    const float* bls = (const float*)d_in[9];

    const int N = in_sizes[0] / 128;   // 100000
    const int E = in_sizes[1] / 2;     // 1600000
    const int Np1 = N + 1;
    const int NCB = (N + CBSZ - 1) / CBSZ;   // 782 coarse buckets
    const int PADMAX = E + 15 * ((N + 15) / 16) * 16 + 64;
    const int* src  = ei;
    const int* dstp = ei + E;

    auto align64 = [](size_t v) { return (v + 63) & ~(size_t)63; };
    char* ws = (char*)d_ws;
    int*   dpad   = (int*)ws;   ws += align64((size_t)N * 4);
    float* dis    = (float*)ws; ws += align64((size_t)N * 4);
    int*   cbin   = (int*)ws;   ws += align64(1024 * 4);
    int*   cboff  = (int*)ws;   ws += align64(1025 * 4);
    int*   ccur16 = (int*)ws;   ws += align64((size_t)1024 * 16 * 4);
    int*   bsum   = (int*)ws;   ws += 4096;
    int*   rp     = (int*)ws;   ws += align64((size_t)(N + 1) * 4);
    int*   ssrc   = (int*)ws;   ws += align64((size_t)PADMAX * 4);
    // sliced feature buffers: 4 slices x (N+1) rows x 32B = (N+1)*128 B each
    unsigned short* bufA = (unsigned short*)ws; ws += align64((size_t)Np1 * 128);
    unsigned short* bufB = (unsigned short*)ws; ws += align64((size_t)Np1 * 128);
    unsigned* pairs = (unsigned*)ws;            ws += align64((size_t)E * 4);
    ws += align64((size_t)N * 64 * 4 - (size_t)E * 4 + 64);  // extension for h1
    // overlays: h1 (f32, 25.6MB) = pairs region + extension (pairs dead after scat2)
    //           g  (f32, 25.6MB) = bufB + pairs region (both dead by head stage)
    float* h1buf = (float*)pairs;
    float* gbuf  = (float*)bufB;

    float* mu = (float*)d_out;
    float* ls = mu + (size_t)N * 32;

    const int nblocks = (N + 255) / 256;             // 391
    const int s1blocks = (E + CHUNK - 1) / CHUNK;    // 391
    const int aggblocks = 2048;

    // ---- 2-level counting sort into padded CSR ----
    hipMemsetAsync(cbin, 0, 1024 * sizeof(int), stream);
    chist_kernel<<<256, 256, 0, stream>>>(dstp, cbin, E, NCB);
    cscan_kernel<<<1, 256, 0, stream>>>(cbin, cboff, ccur16, NCB);
    scat1_kernel<<<s1blocks, 256, 0, stream>>>(src, dstp, ccur16, pairs, E);
    degbuild_kernel<<<NCB, 256, 0, stream>>>(pairs, cboff, dis, dpad, N);
    scan_block_sums<<<nblocks, 256, 0, stream>>>(dpad, bsum, N);
    scan_partials<<<1, 512, 0, stream>>>(bsum, nblocks, rp + N);
    scan_final<<<nblocks, 256, 0, stream>>>(dpad, bsum, rp, N);
    scat2_kernel<<<NCB, 256, 0, stream>>>(pairs, cboff, rp, ssrc, N);

    // ---- dummy row (node N) zero in both sliced buffers ----
    zerorow_kernel<<<1, 64, 0, stream>>>((unsigned*)bufA, (unsigned*)bufB, N, Np1);

    // ---- layer 1: Hs1 (sliced) = (x@W1)*dis ; h1 = leaky(dis*agg + b1) (f32) ----
    gemm1s_kernel<<<N / 16, 256, 0, stream>>>(x, W1, dis, bufA, N, Np1);
    for (int s = 0; s < 4; ++s)
        sgather_kernel<0><<<aggblocks, 256, 0, stream>>>((const unsigned*)bufA, rp, ssrc,
                                                         dis, b1, h1buf, N, Np1, s);

    // ---- Hs2 (sliced) = (h1@W2)*dis ----
    gemmA_kernel<<<N / 16, 256, 0, stream>>>(h1buf, W2, dis, bufB, N, Np1);

    // ---- layer 2: h2s (sliced, in bufA) = leaky(dis*agg(Hs2) + b2)*dis ----
    for (int s = 0; s < 4; ++s)
        sgather_kernel<1><<<aggblocks, 256, 0, stream>>>((const unsigned*)bufB, rp, ssrc,
                                                         dis, b2, bufA, N, Np1, s);

    // ---- head: g (f32) = dis*agg(h2s) ----
    for (int s = 0; s < 4; ++s)
        sgather_kernel<2><<<aggblocks, 256, 0, stream>>>((const unsigned*)bufA, rp, ssrc,
                                                         dis, nullptr, gbuf, N, Np1, s);

    // ---- mu/ls = g@[Wmu|Wls] + b ----
    gemmC_kernel<<<N / 16, 256, 0, stream>>>(gbuf, Wmu, bmu, Wls, bls, mu, ls, N);
}

// Round 10
// 337.436 us; speedup vs baseline: 1.4354x; 1.4354x over previous
//
#include <hip/hip_runtime.h>

#define LEAKY_SLOPE 0.01f
#define CBSH 7
#define CBSZ 128          // nodes per coarse bucket
#define CHUNK 4096        // edges per scat1 block
#define SLACK 2048        // per-bucket padding slack (>= 128*15 = 1920)

__device__ __forceinline__ unsigned short f2bf(float f) {
    unsigned int u = __builtin_bit_cast(unsigned int, f);
    u = (u + 0x7FFFu + ((u >> 16) & 1u)) >> 16;   // round-to-nearest-even
    return (unsigned short)u;
}
__device__ __forceinline__ float bf2f(unsigned short h) {
    return __builtin_bit_cast(float, ((unsigned int)h) << 16);
}
__device__ __forceinline__ float ulof(unsigned u) {
    return __builtin_bit_cast(float, u << 16);
}
__device__ __forceinline__ float uhif(unsigned u) {
    return __builtin_bit_cast(float, u & 0xFFFF0000u);
}
__device__ __forceinline__ float bcastf(int hb, int k) {
    return __builtin_bit_cast(float, __builtin_amdgcn_readlane(hb, k));
}

// ---------------------------------------------------------------------------
// coarse histogram by dst>>7 (LDS-privatized)
// ---------------------------------------------------------------------------
__global__ __launch_bounds__(256) void chist_kernel(const int* __restrict__ dst,
                                                    int* __restrict__ cbin, int E, int ncb) {
    __shared__ int bins[1024];
    for (int i = threadIdx.x; i < 1024; i += 256) bins[i] = 0;
    __syncthreads();
    int stride = gridDim.x * blockDim.x;
    for (int e = blockIdx.x * blockDim.x + threadIdx.x; e < E; e += stride)
        atomicAdd(&bins[dst[e] >> CBSH], 1);
    __syncthreads();
    for (int i = threadIdx.x; i < ncb; i += 256) {
        int v = bins[i];
        if (v) atomicAdd(&cbin[i], v);
    }
}

// single-block scan of coarse bins -> offsets + 64B-strided cursor init
__global__ __launch_bounds__(256) void cscan_kernel(const int* __restrict__ cbin,
                                                    int* __restrict__ cboff,
                                                    int* __restrict__ ccur16, int ncb) {
    __shared__ int s[256];
    __shared__ int carry;
    int t = threadIdx.x;
    if (t == 0) carry = 0;
    __syncthreads();
    for (int base = 0; base < ncb; base += 256) {
        int v = (base + t < ncb) ? cbin[base + t] : 0;
        s[t] = v;
        __syncthreads();
        for (int off = 1; off < 256; off <<= 1) {
            int u = (t >= off) ? s[t - off] : 0;
            __syncthreads();
            s[t] += u;
            __syncthreads();
        }
        int excl = carry + s[t] - v;
        if (base + t < ncb) { cboff[base + t] = excl; ccur16[(size_t)(base + t) * 16] = excl; }
        __syncthreads();
        if (t == 0) carry += s[255];
        __syncthreads();
    }
    if (t == 0) cboff[ncb] = carry;
}

// ---------------------------------------------------------------------------
// blocked level-1 scatter: per-block LDS histogram -> one global atomic per
// (block,bucket) chunk reservation -> LDS-cursor scatter.
// ---------------------------------------------------------------------------
__global__ __launch_bounds__(256) void scat1_kernel(const int* __restrict__ src,
                                                    const int* __restrict__ dst,
                                                    int* __restrict__ ccur16,
                                                    unsigned* __restrict__ pairs, int E) {
    __shared__ int bins[1024];
    __shared__ int base[1024];
    int t = threadIdx.x;
    for (int i = t; i < 1024; i += 256) bins[i] = 0;
    __syncthreads();
    int e0 = blockIdx.x * CHUNK;
    int m = min(CHUNK, E - e0);
    for (int i = t; i < m; i += 256)
        atomicAdd(&bins[dst[e0 + i] >> CBSH], 1);
    __syncthreads();
    for (int i = t; i < 1024; i += 256) {
        int c = bins[i];
        base[i] = c ? atomicAdd(&ccur16[(size_t)i * 16], c) : 0;
        bins[i] = 0;   // reuse as local cursor
    }
    __syncthreads();
    for (int i = t; i < m; i += 256) {
        int d = dst[e0 + i];
        int b = d >> CBSH;
        int off = atomicAdd(&bins[b], 1);
        pairs[base[b] + off] = (unsigned)src[e0 + i] | ((unsigned)(d & (CBSZ - 1)) << 17);
    }
}

// ---------------------------------------------------------------------------
// Fused bucket kernel (replaces degbuild + 3-scan chain + scat2):
// per bucket: LDS degree histogram -> dis, local padded prefix scan ->
// rpS/rcnt, LDS-cursor scatter into the bucket's private padded region,
// pad fill with dummy node n. Bucket region base = cboff[b] + b*SLACK.
// ---------------------------------------------------------------------------
__global__ __launch_bounds__(256) void bucket_kernel(const unsigned* __restrict__ pairs,
                                                     const int* __restrict__ cboff,
                                                     float* __restrict__ dis,
                                                     int* __restrict__ rpS,
                                                     int* __restrict__ rcnt,
                                                     int* __restrict__ ssrc, int n) {
    __shared__ int cnt[CBSZ];
    __shared__ int incl[CBSZ];
    __shared__ int lcur[CBSZ];
    int t = threadIdx.x;
    int b = blockIdx.x;
    if (t < CBSZ) cnt[t] = 0;
    __syncthreads();
    int e0 = cboff[b], e1 = cboff[b + 1];
    for (int e = e0 + t; e < e1; e += 256)
        atomicAdd(&cnt[pairs[e] >> 17], 1);
    __syncthreads();
    if (t < CBSZ) incl[t] = (cnt[t] + 15) & ~15;
    __syncthreads();
    for (int off = 1; off < CBSZ; off <<= 1) {
        int v = 0;
        if (t < CBSZ && t >= off) v = incl[t - off];
        __syncthreads();
        if (t < CBSZ) incl[t] += v;
        __syncthreads();
    }
    int base = e0 + b * SLACK;
    if (t < CBSZ) {
        int pc = (cnt[t] + 15) & ~15;
        int excl = incl[t] - pc;
        lcur[t] = excl;
        int node = b * CBSZ + t;
        if (node < n) {
            rpS[node]  = base + excl;
            rcnt[node] = pc;
            dis[node]  = rsqrtf((float)cnt[t] + 1.0f);
        }
    }
    __syncthreads();
    for (int e = e0 + t; e < e1; e += 256) {
        unsigned p = pairs[e];
        int dl = p >> 17;
        int off = atomicAdd(&lcur[dl], 1);
        ssrc[base + off] = (int)(p & 0x1FFFFu);
    }
    __syncthreads();
    if (t < CBSZ) {
        int node = b * CBSZ + t;
        if (node < n) {
            int c0 = cnt[t];
            int pc = (c0 + 15) & ~15;
            int excl = incl[t] - pc;
            for (int i = excl + c0; i < excl + pc; ++i) ssrc[base + i] = n;
        }
    }
}

// ---------------------------------------------------------------------------
// gemm1: Hs1 = (X[N,128] @ W1[128,64]) * dis -> bf16
// ---------------------------------------------------------------------------
__global__ __launch_bounds__(256) void gemm1_kernel(const float* __restrict__ X,
                                                    const float* __restrict__ W,
                                                    const float* __restrict__ dis,
                                                    unsigned short* __restrict__ Hh, int N) {
    __shared__ float Xs[16 * 128];
    int tid = threadIdx.x;
    int row0 = blockIdx.x * 16;
    for (int i = tid * 4; i < 16 * 128; i += 256 * 4)
        *(float4*)&Xs[i] = *(const float4*)&X[(size_t)row0 * 128 + i];
    __syncthreads();

    int c = tid & 63;
    int g = tid >> 6;
    float acc[4] = {0.f, 0.f, 0.f, 0.f};
    for (int kk = 0; kk < 128; kk += 16) {
        float w[16];
#pragma unroll
        for (int k = 0; k < 16; ++k) w[k] = W[(kk + k) * 64 + c];
#pragma unroll
        for (int r = 0; r < 4; ++r) {
            int row = g + r * 4;
#pragma unroll
            for (int k4 = 0; k4 < 16; k4 += 4) {
                float4 x4 = *(float4*)&Xs[row * 128 + kk + k4];
                acc[r] += x4.x * w[k4] + x4.y * w[k4 + 1] + x4.z * w[k4 + 2] + x4.w * w[k4 + 3];
            }
        }
    }
#pragma unroll
    for (int r = 0; r < 4; ++r) {
        int row = row0 + g + r * 4;
        Hh[(size_t)row * 64 + c] = f2bf(acc[r] * dis[row]);
    }
}

// ---------------------------------------------------------------------------
// Wide gather: 4 lane-groups x 16 lanes; group g consumes the contiguous edge
// quad sp[i+4g..i+4g+3] via ONE int4 load (rcnt padded to x16 -> 16B aligned);
// each lane loads ushort4 (8B). 5 VMEM issues per 16 edges.
// ---------------------------------------------------------------------------
#define GATHER_WIDE(Hh, wid, lane, accv)                                       \
    float accv;                                                                \
    {                                                                          \
        int gg = (lane) >> 4, cc = (lane) & 15;                                \
        float ac0 = 0.f, ac1 = 0.f, ac2 = 0.f, ac3 = 0.f;                      \
        const int* sp = ssrc + rpS[wid];                                       \
        int cnt = rcnt[wid];                                                   \
        for (int i = 0; i < cnt; i += 16) {                                    \
            int4 s4 = *(const int4*)&sp[i + gg * 4];                           \
            uint2 q0 = *(const uint2*)&Hh[(size_t)s4.x * 64 + cc * 4];         \
            uint2 q1 = *(const uint2*)&Hh[(size_t)s4.y * 64 + cc * 4];         \
            uint2 q2 = *(const uint2*)&Hh[(size_t)s4.z * 64 + cc * 4];         \
            uint2 q3 = *(const uint2*)&Hh[(size_t)s4.w * 64 + cc * 4];         \
            ac0 += (ulof(q0.x) + ulof(q1.x)) + (ulof(q2.x) + ulof(q3.x));      \
            ac1 += (uhif(q0.x) + uhif(q1.x)) + (uhif(q2.x) + uhif(q3.x));      \
            ac2 += (ulof(q0.y) + ulof(q1.y)) + (ulof(q2.y) + ulof(q3.y));      \
            ac3 += (uhif(q0.y) + uhif(q1.y)) + (uhif(q2.y) + uhif(q3.y));      \
        }                                                                      \
        ac0 += __shfl_xor(ac0, 16); ac0 += __shfl_xor(ac0, 32);                \
        ac1 += __shfl_xor(ac1, 16); ac1 += __shfl_xor(ac1, 32);                \
        ac2 += __shfl_xor(ac2, 16); ac2 += __shfl_xor(ac2, 32);                \
        ac3 += __shfl_xor(ac3, 16); ac3 += __shfl_xor(ac3, 32);                \
        int srcl = (lane) >> 2;                                                \
        float v0 = __shfl(ac0, srcl);                                          \
        float v1 = __shfl(ac1, srcl);                                          \
        float v2 = __shfl(ac2, srcl);                                          \
        float v3 = __shfl(ac3, srcl);                                          \
        int jj = (lane) & 3;                                                   \
        accv = jj == 0 ? v0 : (jj == 1 ? v1 : (jj == 2 ? v2 : v3));            \
        accv += bf2f(Hh[(size_t)(wid) * 64 + (lane)]);                         \
    }

// LDS matvec epilogue: Ws[k*64+lane] layout, 2 lanes/bank (free), 4-way
// split accumulator chain.
#define LDS_MATVEC(hb, lane, Ws, o)                                            \
    float o;                                                                   \
    {                                                                          \
        float o0 = 0.f, o1 = 0.f, o2 = 0.f, o3 = 0.f;                          \
        _Pragma("unroll")                                                      \
        for (int k = 0; k < 64; k += 4) {                                      \
            o0 = fmaf(bcastf(hb, k),     Ws[(k)*64 + (lane)],     o0);         \
            o1 = fmaf(bcastf(hb, k + 1), Ws[(k+1)*64 + (lane)], o1);           \
            o2 = fmaf(bcastf(hb, k + 2), Ws[(k+2)*64 + (lane)], o2);           \
            o3 = fmaf(bcastf(hb, k + 3), Ws[(k+3)*64 + (lane)], o3);           \
        }                                                                      \
        o = (o0 + o1) + (o2 + o3);                                             \
    }

// ---------------------------------------------------------------------------
// aggA: h1 = leaky(dis*agg(Hs1) + b1); Hs2 = (h1 @ W2)*dis -> bf16
// ---------------------------------------------------------------------------
__global__ __launch_bounds__(256) void aggA_kernel(
    const unsigned short* __restrict__ Hh, const int* __restrict__ rpS,
    const int* __restrict__ rcnt, const int* __restrict__ ssrc,
    const float* __restrict__ dis, const float* __restrict__ b1,
    const float* __restrict__ W2, unsigned short* __restrict__ Oh, int n) {
    __shared__ float Ws[64 * 64];
    for (int i = threadIdx.x * 4; i < 4096; i += 256 * 4)
        *(float4*)&Ws[i] = *(const float4*)&W2[i];
    __syncthreads();

    int lane = threadIdx.x & 63;
    float bias = b1[lane];

    int wid = (int)((blockIdx.x * blockDim.x + threadIdx.x) >> 6);
    int nwaves = (int)((gridDim.x * blockDim.x) >> 6);
    for (; wid < n; wid += nwaves) {
        GATHER_WIDE(Hh, wid, lane, accv)
        float d = dis[wid];
        float h = fmaf(accv, d, bias);
        h = h > 0.f ? h : LEAKY_SLOPE * h;
        int hb = __builtin_bit_cast(int, h);
        LDS_MATVEC(hb, lane, Ws, o)
        Oh[(size_t)wid * 64 + lane] = f2bf(o * d);
    }
}

// ---------------------------------------------------------------------------
// aggB: h2 = leaky(dis*agg(Hs2) + b2); h2s = h2*dis -> bf16
// ---------------------------------------------------------------------------
__global__ __launch_bounds__(256) void aggB_kernel(
    const unsigned short* __restrict__ Hh, const int* __restrict__ rpS,
    const int* __restrict__ rcnt, const int* __restrict__ ssrc,
    const float* __restrict__ dis, const float* __restrict__ b2,
    unsigned short* __restrict__ Oh, int n) {
    int lane = threadIdx.x & 63;
    float bias = b2[lane];
    int wid = (int)((blockIdx.x * blockDim.x + threadIdx.x) >> 6);
    int nwaves = (int)((gridDim.x * blockDim.x) >> 6);
    for (; wid < n; wid += nwaves) {
        GATHER_WIDE(Hh, wid, lane, accv)
        float d = dis[wid];
        float h = fmaf(accv, d, bias);
        h = h > 0.f ? h : LEAKY_SLOPE * h;
        Oh[(size_t)wid * 64 + lane] = f2bf(h * d);
    }
}

// ---------------------------------------------------------------------------
// aggC: g = dis*agg(h2s); mu = g@Wmu + bmu; ls = g@Wls + bls -> d_out
// ---------------------------------------------------------------------------
__global__ __launch_bounds__(256) void aggC_kernel(
    const unsigned short* __restrict__ Hh, const int* __restrict__ rpS,
    const int* __restrict__ rcnt, const int* __restrict__ ssrc,
    const float* __restrict__ dis, const float* __restrict__ Wmu,
    const float* __restrict__ bmu, const float* __restrict__ Wls,
    const float* __restrict__ bls, float* __restrict__ mu,
    float* __restrict__ ls, int n) {
    __shared__ float Ws[64 * 64];
    for (int i = threadIdx.x; i < 4096; i += 256) {
        int k = i >> 6, c = i & 63;
        Ws[i] = (c < 32) ? Wmu[k * 32 + c] : Wls[k * 32 + (c - 32)];
    }
    __syncthreads();

    int lane = threadIdx.x & 63;
    int half = lane >> 5;
    int c = lane & 31;
    float bias = half ? bls[c] : bmu[c];
    float* outp = half ? ls : mu;

    int wid = (int)((blockIdx.x * blockDim.x + threadIdx.x) >> 6);
    int nwaves = (int)((gridDim.x * blockDim.x) >> 6);
    for (; wid < n; wid += nwaves) {
        GATHER_WIDE(Hh, wid, lane, accv)
        float gval = accv * dis[wid];
        int gb = __builtin_bit_cast(int, gval);
        LDS_MATVEC(gb, lane, Ws, o)
        outp[(size_t)wid * 32 + c] = o + bias;
    }
}

// ---------------------------------------------------------------------------
extern "C" void kernel_launch(void* const* d_in, const int* in_sizes, int n_in,
                              void* d_out, int out_size, void* d_ws, size_t ws_size,
                              hipStream_t stream) {
    const float* x   = (const float*)d_in[0];
    const int*   ei  = (const int*)d_in[1];
    const float* W1  = (const float*)d_in[2];
    const float* b1  = (const float*)d_in[3];
    const float* W2  = (const float*)d_in[4];
    const float* b2  = (const float*)d_in[5];
    const float* Wmu = (const float*)d_in[6];
    const float* bmu = (const float*)d_in[7];
    const float* Wls = (const float*)d_in[8];
    const float* bls = (const float*)d_in[9];

    const int N = in_sizes[0] / 128;   // 100000
    const int E = in_sizes[1] / 2;     // 1600000
    const int NCB = (N + CBSZ - 1) / CBSZ;          // 782 coarse buckets
    const int SSRC_SZ = E + NCB * SLACK + 64;       // padded CSR upper bound
    const int* src  = ei;
    const int* dstp = ei + E;

    auto align64 = [](size_t v) { return (v + 63) & ~(size_t)63; };
    char* ws = (char*)d_ws;
    float* dis    = (float*)ws; ws += align64((size_t)N * 4);
    int*   cbin   = (int*)ws;   ws += align64(1024 * 4);
    int*   cboff  = (int*)ws;   ws += align64(1025 * 4);
    int*   ccur16 = (int*)ws;   ws += align64((size_t)1024 * 16 * 4);
    int*   rpS    = (int*)ws;   ws += align64((size_t)N * 4);
    int*   rcnt   = (int*)ws;   ws += align64((size_t)N * 4);
    unsigned* pairs = (unsigned*)ws; ws += align64((size_t)E * 4);
    int*   ssrc   = (int*)ws;   ws += align64((size_t)SSRC_SZ * 4);
    unsigned short* bufH0 = (unsigned short*)ws; ws += align64(((size_t)N + 1) * 64 * 2);
    unsigned short* bufH1 = (unsigned short*)ws; ws += align64(((size_t)N + 1) * 64 * 2);

    float* mu = (float*)d_out;
    float* ls = mu + (size_t)N * 32;

    const int s1blocks = (E + CHUNK - 1) / CHUNK;   // 391

    // ---- 2-level counting sort into per-bucket padded CSR ----
    hipMemsetAsync(cbin, 0, 1024 * sizeof(int), stream);
    chist_kernel<<<1024, 256, 0, stream>>>(dstp, cbin, E, NCB);
    cscan_kernel<<<1, 256, 0, stream>>>(cbin, cboff, ccur16, NCB);
    scat1_kernel<<<s1blocks, 256, 0, stream>>>(src, dstp, ccur16, pairs, E);
    bucket_kernel<<<NCB, 256, 0, stream>>>(pairs, cboff, dis, rpS, rcnt, ssrc, N);

    // ---- Hs1 = (x@W1)*dis (bf16); zero dummy row N in both buffers ----
    gemm1_kernel<<<N / 16, 256, 0, stream>>>(x, W1, dis, bufH0, N);
    hipMemsetAsync(bufH0 + (size_t)N * 64, 0, 128, stream);
    hipMemsetAsync(bufH1 + (size_t)N * 64, 0, 128, stream);

    const int aggblocks = 2048;  // 8192 waves, grid-stride

    aggA_kernel<<<aggblocks, 256, 0, stream>>>(bufH0, rpS, rcnt, ssrc, dis, b1, W2, bufH1, N);
    aggB_kernel<<<aggblocks, 256, 0, stream>>>(bufH1, rpS, rcnt, ssrc, dis, b2, bufH0, N);
    aggC_kernel<<<aggblocks, 256, 0, stream>>>(bufH0, rpS, rcnt, ssrc, dis, Wmu, bmu,
                                               Wls, bls, mu, ls, N);
}

// Round 11
// 289.497 us; speedup vs baseline: 1.6731x; 1.1656x over previous
//
#include <hip/hip_runtime.h>

#define LEAKY_SLOPE 0.01f
#define CBSH 7
#define CBSZ 128          // nodes per coarse bucket
#define CHUNK 4096        // edges per scat1 block
#define NCBMAX 1024
#define CAP 2560          // static per-bucket pairs capacity (mean 2046, 11 sigma)
#define PADCAP 4480       // CAP + 128*15 pad slack, multiple of 16 (64B aligned)

__device__ __forceinline__ unsigned short f2bf(float f) {
    unsigned int u = __builtin_bit_cast(unsigned int, f);
    u = (u + 0x7FFFu + ((u >> 16) & 1u)) >> 16;   // round-to-nearest-even
    return (unsigned short)u;
}
__device__ __forceinline__ float bf2f(unsigned short h) {
    return __builtin_bit_cast(float, ((unsigned int)h) << 16);
}
__device__ __forceinline__ float ulof(unsigned u) {
    return __builtin_bit_cast(float, u << 16);
}
__device__ __forceinline__ float uhif(unsigned u) {
    return __builtin_bit_cast(float, u & 0xFFFF0000u);
}
__device__ __forceinline__ float bcastf(int hb, int k) {
    return __builtin_bit_cast(float, __builtin_amdgcn_readlane(hb, k));
}

// ---------------------------------------------------------------------------
// init 64B-strided bucket cursors to static bases b*CAP
// ---------------------------------------------------------------------------
__global__ void initcur_kernel(int* __restrict__ ccur16, int ncb) {
    int b = blockIdx.x * blockDim.x + threadIdx.x;
    if (b < ncb) ccur16[(size_t)b * 16] = b * CAP;
}

// ---------------------------------------------------------------------------
// blocked level-1 scatter: per-block LDS histogram -> one global atomic per
// (block,bucket) chunk reservation -> LDS-cursor scatter into static regions.
// ---------------------------------------------------------------------------
__global__ __launch_bounds__(256) void scat1_kernel(const int* __restrict__ src,
                                                    const int* __restrict__ dst,
                                                    int* __restrict__ ccur16,
                                                    unsigned* __restrict__ pairs, int E) {
    __shared__ int bins[NCBMAX];
    __shared__ int base[NCBMAX];
    int t = threadIdx.x;
    for (int i = t; i < NCBMAX; i += 256) bins[i] = 0;
    __syncthreads();
    int e0 = blockIdx.x * CHUNK;
    int m = min(CHUNK, E - e0);
    for (int i = t; i < m; i += 256)
        atomicAdd(&bins[dst[e0 + i] >> CBSH], 1);
    __syncthreads();
    for (int i = t; i < NCBMAX; i += 256) {
        int c = bins[i];
        base[i] = c ? atomicAdd(&ccur16[(size_t)i * 16], c) : 0;
        bins[i] = 0;   // reuse as local cursor
    }
    __syncthreads();
    for (int i = t; i < m; i += 256) {
        int d = dst[e0 + i];
        int b = d >> CBSH;
        int off = atomicAdd(&bins[b], 1);
        pairs[base[b] + off] = (unsigned)src[e0 + i] | ((unsigned)(d & (CBSZ - 1)) << 17);
    }
}

// ---------------------------------------------------------------------------
// Fused bucket kernel: per bucket LDS degree histogram -> dis, local padded
// prefix scan -> rpS/rcnt (bases 64B-aligned: b*PADCAP + excl*4, excl % 16 == 0),
// LDS-cursor scatter into the bucket's private padded region, pad fill with
// dummy node n. Edge count read from the bucket's post-scat1 cursor.
// ---------------------------------------------------------------------------
__global__ __launch_bounds__(256) void bucket_kernel(const unsigned* __restrict__ pairs,
                                                     const int* __restrict__ ccur16,
                                                     float* __restrict__ dis,
                                                     int* __restrict__ rpS,
                                                     int* __restrict__ rcnt,
                                                     int* __restrict__ ssrc, int n) {
    __shared__ int cnt[CBSZ];
    __shared__ int incl[CBSZ];
    __shared__ int lcur[CBSZ];
    int t = threadIdx.x;
    int b = blockIdx.x;
    if (t < CBSZ) cnt[t] = 0;
    __syncthreads();
    int e0 = b * CAP;
    int e1 = ccur16[(size_t)b * 16];   // end cursor after scat1
    for (int e = e0 + t; e < e1; e += 256)
        atomicAdd(&cnt[pairs[e] >> 17], 1);
    __syncthreads();
    if (t < CBSZ) incl[t] = (cnt[t] + 15) & ~15;
    __syncthreads();
    for (int off = 1; off < CBSZ; off <<= 1) {
        int v = 0;
        if (t < CBSZ && t >= off) v = incl[t - off];
        __syncthreads();
        if (t < CBSZ) incl[t] += v;
        __syncthreads();
    }
    int base = b * PADCAP;
    if (t < CBSZ) {
        int pc = (cnt[t] + 15) & ~15;
        int excl = incl[t] - pc;
        lcur[t] = excl;
        int node = b * CBSZ + t;
        if (node < n) {
            rpS[node]  = base + excl;
            rcnt[node] = pc;
            dis[node]  = rsqrtf((float)cnt[t] + 1.0f);
        }
    }
    __syncthreads();
    for (int e = e0 + t; e < e1; e += 256) {
        unsigned p = pairs[e];
        int dl = p >> 17;
        int off = atomicAdd(&lcur[dl], 1);
        ssrc[base + off] = (int)(p & 0x1FFFFu);
    }
    __syncthreads();
    if (t < CBSZ) {
        int node = b * CBSZ + t;
        if (node < n) {
            int c0 = cnt[t];
            int pc = (c0 + 15) & ~15;
            int excl = incl[t] - pc;
            for (int i = excl + c0; i < excl + pc; ++i) ssrc[base + i] = n;
        }
    }
}

// ---------------------------------------------------------------------------
// gemm1: Hs1 = (X[N,128] @ W1[128,64]) * dis -> bf16
// ---------------------------------------------------------------------------
__global__ __launch_bounds__(256) void gemm1_kernel(const float* __restrict__ X,
                                                    const float* __restrict__ W,
                                                    const float* __restrict__ dis,
                                                    unsigned short* __restrict__ Hh, int N) {
    __shared__ float Xs[16 * 128];
    int tid = threadIdx.x;
    int row0 = blockIdx.x * 16;
    for (int i = tid * 4; i < 16 * 128; i += 256 * 4)
        *(float4*)&Xs[i] = *(const float4*)&X[(size_t)row0 * 128 + i];
    __syncthreads();

    int c = tid & 63;
    int g = tid >> 6;
    float acc[4] = {0.f, 0.f, 0.f, 0.f};
    for (int kk = 0; kk < 128; kk += 16) {
        float w[16];
#pragma unroll
        for (int k = 0; k < 16; ++k) w[k] = W[(kk + k) * 64 + c];
#pragma unroll
        for (int r = 0; r < 4; ++r) {
            int row = g + r * 4;
#pragma unroll
            for (int k4 = 0; k4 < 16; k4 += 4) {
                float4 x4 = *(float4*)&Xs[row * 128 + kk + k4];
                acc[r] += x4.x * w[k4] + x4.y * w[k4 + 1] + x4.z * w[k4 + 2] + x4.w * w[k4 + 3];
            }
        }
    }
#pragma unroll
    for (int r = 0; r < 4; ++r) {
        int row = row0 + g + r * 4;
        Hh[(size_t)row * 64 + c] = f2bf(acc[r] * dis[row]);
    }
}

// ---------------------------------------------------------------------------
// Wide gather: 4 lane-groups x 16 lanes; group g consumes the contiguous edge
// quad sp[i+4g..i+4g+3] via ONE int4 load (lists 64B-aligned); each lane loads
// ushort4 (8B). 5 VMEM issues per 16 edges.
// ---------------------------------------------------------------------------
#define GATHER_WIDE(Hh, wid, lane, accv)                                       \
    float accv;                                                                \
    {                                                                          \
        int gg = (lane) >> 4, cc = (lane) & 15;                                \
        float ac0 = 0.f, ac1 = 0.f, ac2 = 0.f, ac3 = 0.f;                      \
        const int* sp = ssrc + rpS[wid];                                       \
        int cnt = rcnt[wid];                                                   \
        for (int i = 0; i < cnt; i += 16) {                                    \
            int4 s4 = *(const int4*)&sp[i + gg * 4];                           \
            uint2 q0 = *(const uint2*)&Hh[(size_t)s4.x * 64 + cc * 4];         \
            uint2 q1 = *(const uint2*)&Hh[(size_t)s4.y * 64 + cc * 4];         \
            uint2 q2 = *(const uint2*)&Hh[(size_t)s4.z * 64 + cc * 4];         \
            uint2 q3 = *(const uint2*)&Hh[(size_t)s4.w * 64 + cc * 4];         \
            ac0 += (ulof(q0.x) + ulof(q1.x)) + (ulof(q2.x) + ulof(q3.x));      \
            ac1 += (uhif(q0.x) + uhif(q1.x)) + (uhif(q2.x) + uhif(q3.x));      \
            ac2 += (ulof(q0.y) + ulof(q1.y)) + (ulof(q2.y) + ulof(q3.y));      \
            ac3 += (uhif(q0.y) + uhif(q1.y)) + (uhif(q2.y) + uhif(q3.y));      \
        }                                                                      \
        ac0 += __shfl_xor(ac0, 16); ac0 += __shfl_xor(ac0, 32);                \
        ac1 += __shfl_xor(ac1, 16); ac1 += __shfl_xor(ac1, 32);                \
        ac2 += __shfl_xor(ac2, 16); ac2 += __shfl_xor(ac2, 32);                \
        ac3 += __shfl_xor(ac3, 16); ac3 += __shfl_xor(ac3, 32);                \
        int srcl = (lane) >> 2;                                                \
        float v0 = __shfl(ac0, srcl);                                          \
        float v1 = __shfl(ac1, srcl);                                          \
        float v2 = __shfl(ac2, srcl);                                          \
        float v3 = __shfl(ac3, srcl);                                          \
        int jj = (lane) & 3;                                                   \
        accv = jj == 0 ? v0 : (jj == 1 ? v1 : (jj == 2 ? v2 : v3));            \
        accv += bf2f(Hh[(size_t)(wid) * 64 + (lane)]);                         \
    }

// LDS matvec epilogue: Ws[k*64+lane] layout, 2 lanes/bank (free), 4-way
// split accumulator chain.
#define LDS_MATVEC(hb, lane, Ws, o)                                            \
    float o;                                                                   \
    {                                                                          \
        float o0 = 0.f, o1 = 0.f, o2 = 0.f, o3 = 0.f;                          \
        _Pragma("unroll")                                                      \
        for (int k = 0; k < 64; k += 4) {                                      \
            o0 = fmaf(bcastf(hb, k),     Ws[(k)*64 + (lane)],     o0);         \
            o1 = fmaf(bcastf(hb, k + 1), Ws[(k+1)*64 + (lane)], o1);           \
            o2 = fmaf(bcastf(hb, k + 2), Ws[(k+2)*64 + (lane)], o2);           \
            o3 = fmaf(bcastf(hb, k + 3), Ws[(k+3)*64 + (lane)], o3);           \
        }                                                                      \
        o = (o0 + o1) + (o2 + o3);                                             \
    }

// ---------------------------------------------------------------------------
// aggA: h1 = leaky(dis*agg(Hs1) + b1); Hs2 = (h1 @ W2)*dis -> bf16
// ---------------------------------------------------------------------------
__global__ __launch_bounds__(256) void aggA_kernel(
    const unsigned short* __restrict__ Hh, const int* __restrict__ rpS,
    const int* __restrict__ rcnt, const int* __restrict__ ssrc,
    const float* __restrict__ dis, const float* __restrict__ b1,
    const float* __restrict__ W2, unsigned short* __restrict__ Oh, int n) {
    __shared__ float Ws[64 * 64];
    for (int i = threadIdx.x * 4; i < 4096; i += 256 * 4)
        *(float4*)&Ws[i] = *(const float4*)&W2[i];
    __syncthreads();

    int lane = threadIdx.x & 63;
    float bias = b1[lane];

    int wid = (int)((blockIdx.x * blockDim.x + threadIdx.x) >> 6);
    int nwaves = (int)((gridDim.x * blockDim.x) >> 6);
    for (; wid < n; wid += nwaves) {
        GATHER_WIDE(Hh, wid, lane, accv)
        float d = dis[wid];
        float h = fmaf(accv, d, bias);
        h = h > 0.f ? h : LEAKY_SLOPE * h;
        int hb = __builtin_bit_cast(int, h);
        LDS_MATVEC(hb, lane, Ws, o)
        Oh[(size_t)wid * 64 + lane] = f2bf(o * d);
    }
}

// ---------------------------------------------------------------------------
// aggB: h2 = leaky(dis*agg(Hs2) + b2); h2s = h2*dis -> bf16
// ---------------------------------------------------------------------------
__global__ __launch_bounds__(256) void aggB_kernel(
    const unsigned short* __restrict__ Hh, const int* __restrict__ rpS,
    const int* __restrict__ rcnt, const int* __restrict__ ssrc,
    const float* __restrict__ dis, const float* __restrict__ b2,
    unsigned short* __restrict__ Oh, int n) {
    int lane = threadIdx.x & 63;
    float bias = b2[lane];
    int wid = (int)((blockIdx.x * blockDim.x + threadIdx.x) >> 6);
    int nwaves = (int)((gridDim.x * blockDim.x) >> 6);
    for (; wid < n; wid += nwaves) {
        GATHER_WIDE(Hh, wid, lane, accv)
        float d = dis[wid];
        float h = fmaf(accv, d, bias);
        h = h > 0.f ? h : LEAKY_SLOPE * h;
        Oh[(size_t)wid * 64 + lane] = f2bf(h * d);
    }
}

// ---------------------------------------------------------------------------
// aggC: g = dis*agg(h2s); mu = g@Wmu + bmu; ls = g@Wls + bls -> d_out
// ---------------------------------------------------------------------------
__global__ __launch_bounds__(256) void aggC_kernel(
    const unsigned short* __restrict__ Hh, const int* __restrict__ rpS,
    const int* __restrict__ rcnt, const int* __restrict__ ssrc,
    const float* __restrict__ dis, const float* __restrict__ Wmu,
    const float* __restrict__ bmu, const float* __restrict__ Wls,
    const float* __restrict__ bls, float* __restrict__ mu,
    float* __restrict__ ls, int n) {
    __shared__ float Ws[64 * 64];
    for (int i = threadIdx.x; i < 4096; i += 256) {
        int k = i >> 6, c = i & 63;
        Ws[i] = (c < 32) ? Wmu[k * 32 + c] : Wls[k * 32 + (c - 32)];
    }
    __syncthreads();

    int lane = threadIdx.x & 63;
    int half = lane >> 5;
    int c = lane & 31;
    float bias = half ? bls[c] : bmu[c];
    float* outp = half ? ls : mu;

    int wid = (int)((blockIdx.x * blockDim.x + threadIdx.x) >> 6);
    int nwaves = (int)((gridDim.x * blockDim.x) >> 6);
    for (; wid < n; wid += nwaves) {
        GATHER_WIDE(Hh, wid, lane, accv)
        float gval = accv * dis[wid];
        int gb = __builtin_bit_cast(int, gval);
        LDS_MATVEC(gb, lane, Ws, o)
        outp[(size_t)wid * 32 + c] = o + bias;
    }
}

// ---------------------------------------------------------------------------
extern "C" void kernel_launch(void* const* d_in, const int* in_sizes, int n_in,
                              void* d_out, int out_size, void* d_ws, size_t ws_size,
                              hipStream_t stream) {
    const float* x   = (const float*)d_in[0];
    const int*   ei  = (const int*)d_in[1];
    const float* W1  = (const float*)d_in[2];
    const float* b1  = (const float*)d_in[3];
    const float* W2  = (const float*)d_in[4];
    const float* b2  = (const float*)d_in[5];
    const float* Wmu = (const float*)d_in[6];
    const float* bmu = (const float*)d_in[7];
    const float* Wls = (const float*)d_in[8];
    const float* bls = (const float*)d_in[9];

    const int N = in_sizes[0] / 128;   // 100000
    const int E = in_sizes[1] / 2;     // 1600000
    const int NCB = (N + CBSZ - 1) / CBSZ;   // 782 coarse buckets
    const int* src  = ei;
    const int* dstp = ei + E;

    auto align64 = [](size_t v) { return (v + 63) & ~(size_t)63; };
    char* ws = (char*)d_ws;
    float* dis    = (float*)ws; ws += align64((size_t)N * 4);
    int*   ccur16 = (int*)ws;   ws += align64((size_t)NCBMAX * 16 * 4);
    int*   rpS    = (int*)ws;   ws += align64((size_t)N * 4);
    int*   rcnt   = (int*)ws;   ws += align64((size_t)N * 4);
    unsigned* pairs = (unsigned*)ws; ws += align64((size_t)NCB * CAP * 4);
    int*   ssrc   = (int*)ws;   ws += align64((size_t)NCB * PADCAP * 4);
    unsigned short* bufH0 = (unsigned short*)ws; ws += align64(((size_t)N + 1) * 64 * 2);
    unsigned short* bufH1 = (unsigned short*)ws; ws += align64(((size_t)N + 1) * 64 * 2);

    float* mu = (float*)d_out;
    float* ls = mu + (size_t)N * 32;

    const int s1blocks = (E + CHUNK - 1) / CHUNK;   // 391

    // ---- counting sort into static 64B-aligned per-bucket padded CSR ----
    initcur_kernel<<<(NCB + 255) / 256, 256, 0, stream>>>(ccur16, NCB);
    scat1_kernel<<<s1blocks, 256, 0, stream>>>(src, dstp, ccur16, pairs, E);
    bucket_kernel<<<NCB, 256, 0, stream>>>(pairs, ccur16, dis, rpS, rcnt, ssrc, N);

    // ---- Hs1 = (x@W1)*dis (bf16); zero dummy row N in both buffers ----
    gemm1_kernel<<<N / 16, 256, 0, stream>>>(x, W1, dis, bufH0, N);
    hipMemsetAsync(bufH0 + (size_t)N * 64, 0, 128, stream);
    hipMemsetAsync(bufH1 + (size_t)N * 64, 0, 128, stream);

    const int aggblocks = 2048;  // 8192 waves, grid-stride

    aggA_kernel<<<aggblocks, 256, 0, stream>>>(bufH0, rpS, rcnt, ssrc, dis, b1, W2, bufH1, N);
    aggB_kernel<<<aggblocks, 256, 0, stream>>>(bufH1, rpS, rcnt, ssrc, dis, b2, bufH0, N);
    aggC_kernel<<<aggblocks, 256, 0, stream>>>(bufH0, rpS, rcnt, ssrc, dis, Wmu, bmu,
                                               Wls, bls, mu, ls, N);
}

// Round 12
// 281.000 us; speedup vs baseline: 1.7237x; 1.0302x over previous
//
#include <hip/hip_runtime.h>

#define LEAKY_SLOPE 0.01f
#define CBSH 7
#define CBSZ 128          // nodes per coarse bucket
#define CHUNK 4096        // edges per scat1 block
#define NCBMAX 1024
#define CAP 2560          // static per-bucket pairs capacity (mean 2046, 11 sigma)
#define PADCAP 4480       // CAP + 128*15 pad slack, multiple of 16 (64B aligned)

__device__ __forceinline__ unsigned short f2bf(float f) {
    unsigned int u = __builtin_bit_cast(unsigned int, f);
    u = (u + 0x7FFFu + ((u >> 16) & 1u)) >> 16;   // round-to-nearest-even
    return (unsigned short)u;
}
__device__ __forceinline__ float bf2f(unsigned short h) {
    return __builtin_bit_cast(float, ((unsigned int)h) << 16);
}
__device__ __forceinline__ float ulof(unsigned u) {
    return __builtin_bit_cast(float, u << 16);
}
__device__ __forceinline__ float uhif(unsigned u) {
    return __builtin_bit_cast(float, u & 0xFFFF0000u);
}
__device__ __forceinline__ float bcastf(int hb, int k) {
    return __builtin_bit_cast(float, __builtin_amdgcn_readlane(hb, k));
}

// ---------------------------------------------------------------------------
// init 64B-strided bucket cursors to static bases b*CAP
// ---------------------------------------------------------------------------
__global__ void initcur_kernel(int* __restrict__ ccur16, int ncb) {
    int b = blockIdx.x * blockDim.x + threadIdx.x;
    if (b < ncb) ccur16[(size_t)b * 16] = b * CAP;
}

// ---------------------------------------------------------------------------
// blocked level-1 scatter: dst cached in 16 named registers across both
// passes (no L2 re-read); per-block LDS histogram -> one global atomic per
// (block,bucket) reservation -> LDS-cursor scatter into static regions.
// ---------------------------------------------------------------------------
__global__ __launch_bounds__(256) void scat1_kernel(const int* __restrict__ src,
                                                    const int* __restrict__ dst,
                                                    int* __restrict__ ccur16,
                                                    unsigned* __restrict__ pairs, int E) {
    __shared__ int bins[NCBMAX];
    __shared__ int base[NCBMAX];
    int t = threadIdx.x;
    for (int i = t; i < NCBMAX; i += 256) bins[i] = 0;

    int e0 = blockIdx.x * CHUNK;
    int m = min(CHUNK, E - e0);
    int dd[16];
#pragma unroll
    for (int j = 0; j < 16; ++j) {
        int i = t + j * 256;
        dd[j] = (i < m) ? dst[e0 + i] : -1;
    }
    __syncthreads();
#pragma unroll
    for (int j = 0; j < 16; ++j)
        if (dd[j] >= 0) atomicAdd(&bins[dd[j] >> CBSH], 1);
    __syncthreads();
    for (int i = t; i < NCBMAX; i += 256) {
        int c = bins[i];
        base[i] = c ? atomicAdd(&ccur16[(size_t)i * 16], c) : 0;
        bins[i] = 0;   // reuse as local cursor
    }
    __syncthreads();
#pragma unroll
    for (int j = 0; j < 16; ++j) {
        if (dd[j] >= 0) {
            int d = dd[j];
            int b = d >> CBSH;
            int off = atomicAdd(&bins[b], 1);
            pairs[base[b] + off] =
                (unsigned)src[e0 + t + j * 256] | ((unsigned)(d & (CBSZ - 1)) << 17);
        }
    }
}

// ---------------------------------------------------------------------------
// Fused bucket kernel: per bucket LDS degree histogram -> dis, local padded
// prefix scan -> rpS/rcnt (bases 64B-aligned), LDS-cursor scatter into the
// bucket's private padded region, pad fill with dummy node n.
// ---------------------------------------------------------------------------
__global__ __launch_bounds__(256) void bucket_kernel(const unsigned* __restrict__ pairs,
                                                     const int* __restrict__ ccur16,
                                                     float* __restrict__ dis,
                                                     int* __restrict__ rpS,
                                                     int* __restrict__ rcnt,
                                                     int* __restrict__ ssrc, int n) {
    __shared__ int cnt[CBSZ];
    __shared__ int incl[CBSZ];
    __shared__ int lcur[CBSZ];
    int t = threadIdx.x;
    int b = blockIdx.x;
    if (t < CBSZ) cnt[t] = 0;
    __syncthreads();
    int e0 = b * CAP;
    int e1 = ccur16[(size_t)b * 16];   // end cursor after scat1
    for (int e = e0 + t; e < e1; e += 256)
        atomicAdd(&cnt[pairs[e] >> 17], 1);
    __syncthreads();
    if (t < CBSZ) incl[t] = (cnt[t] + 15) & ~15;
    __syncthreads();
    for (int off = 1; off < CBSZ; off <<= 1) {
        int v = 0;
        if (t < CBSZ && t >= off) v = incl[t - off];
        __syncthreads();
        if (t < CBSZ) incl[t] += v;
        __syncthreads();
    }
    int base = b * PADCAP;
    if (t < CBSZ) {
        int pc = (cnt[t] + 15) & ~15;
        int excl = incl[t] - pc;
        lcur[t] = excl;
        int node = b * CBSZ + t;
        if (node < n) {
            rpS[node]  = base + excl;
            rcnt[node] = pc;
            dis[node]  = rsqrtf((float)cnt[t] + 1.0f);
        }
    }
    __syncthreads();
    for (int e = e0 + t; e < e1; e += 256) {
        unsigned p = pairs[e];
        int dl = p >> 17;
        int off = atomicAdd(&lcur[dl], 1);
        ssrc[base + off] = (int)(p & 0x1FFFFu);
    }
    __syncthreads();
    if (t < CBSZ) {
        int node = b * CBSZ + t;
        if (node < n) {
            int c0 = cnt[t];
            int pc = (c0 + 15) & ~15;
            int excl = incl[t] - pc;
            for (int i = excl + c0; i < excl + pc; ++i) ssrc[base + i] = n;
        }
    }
}

// ---------------------------------------------------------------------------
// gemm1: Hs1 = (X[N,128] @ W1[128,64]) * dis -> bf16.
// 32 rows/block, 8 rows/thread (FMA:load ratio 2x vs 4-row version).
// Block 0 also zeroes the dummy row n in both feature buffers.
// ---------------------------------------------------------------------------
__global__ __launch_bounds__(256) void gemm1_kernel(const float* __restrict__ X,
                                                    const float* __restrict__ W,
                                                    const float* __restrict__ dis,
                                                    unsigned short* __restrict__ Hh,
                                                    unsigned short* __restrict__ Hh2,
                                                    int N) {
    __shared__ float Xs[32 * 128];
    int tid = threadIdx.x;
    if (blockIdx.x == 0 && tid < 64) {
        Hh[(size_t)N * 64 + tid] = 0;
        Hh2[(size_t)N * 64 + tid] = 0;
    }
    int row0 = blockIdx.x * 32;
    for (int i = tid * 4; i < 32 * 128; i += 256 * 4)
        *(float4*)&Xs[i] = *(const float4*)&X[(size_t)row0 * 128 + i];
    __syncthreads();

    int c = tid & 63;
    int g = tid >> 6;   // 4 groups; group g owns rows g, g+4, ..., g+28
    float acc[8];
#pragma unroll
    for (int r = 0; r < 8; ++r) acc[r] = 0.f;

    for (int kk = 0; kk < 128; kk += 16) {
        float w[16];
#pragma unroll
        for (int k = 0; k < 16; ++k) w[k] = W[(kk + k) * 64 + c];
#pragma unroll
        for (int r = 0; r < 8; ++r) {
            int row = g + r * 4;
#pragma unroll
            for (int k4 = 0; k4 < 16; k4 += 4) {
                float4 x4 = *(float4*)&Xs[row * 128 + kk + k4];
                acc[r] += x4.x * w[k4] + x4.y * w[k4 + 1] + x4.z * w[k4 + 2] + x4.w * w[k4 + 3];
            }
        }
    }
#pragma unroll
    for (int r = 0; r < 8; ++r) {
        int row = row0 + g + r * 4;
        Hh[(size_t)row * 64 + c] = f2bf(acc[r] * dis[row]);
    }
}

// ---------------------------------------------------------------------------
// Wide gather: 4 lane-groups x 16 lanes; group g consumes the contiguous edge
// quad sp[i+4g..i+4g+3] via ONE int4 load (lists 64B-aligned); each lane loads
// ushort4 (8B). 5 VMEM issues per 16 edges.
// ---------------------------------------------------------------------------
#define GATHER_WIDE(Hh, wid, lane, accv)                                       \
    float accv;                                                                \
    {                                                                          \
        int gg = (lane) >> 4, cc = (lane) & 15;                                \
        float ac0 = 0.f, ac1 = 0.f, ac2 = 0.f, ac3 = 0.f;                      \
        const int* sp = ssrc + rpS[wid];                                       \
        int cnt = rcnt[wid];                                                   \
        for (int i = 0; i < cnt; i += 16) {                                    \
            int4 s4 = *(const int4*)&sp[i + gg * 4];                           \
            uint2 q0 = *(const uint2*)&Hh[(size_t)s4.x * 64 + cc * 4];         \
            uint2 q1 = *(const uint2*)&Hh[(size_t)s4.y * 64 + cc * 4];         \
            uint2 q2 = *(const uint2*)&Hh[(size_t)s4.z * 64 + cc * 4];         \
            uint2 q3 = *(const uint2*)&Hh[(size_t)s4.w * 64 + cc * 4];         \
            ac0 += (ulof(q0.x) + ulof(q1.x)) + (ulof(q2.x) + ulof(q3.x));      \
            ac1 += (uhif(q0.x) + uhif(q1.x)) + (uhif(q2.x) + uhif(q3.x));      \
            ac2 += (ulof(q0.y) + ulof(q1.y)) + (ulof(q2.y) + ulof(q3.y));      \
            ac3 += (uhif(q0.y) + uhif(q1.y)) + (uhif(q2.y) + uhif(q3.y));      \
        }                                                                      \
        ac0 += __shfl_xor(ac0, 16); ac0 += __shfl_xor(ac0, 32);                \
        ac1 += __shfl_xor(ac1, 16); ac1 += __shfl_xor(ac1, 32);                \
        ac2 += __shfl_xor(ac2, 16); ac2 += __shfl_xor(ac2, 32);                \
        ac3 += __shfl_xor(ac3, 16); ac3 += __shfl_xor(ac3, 32);                \
        int srcl = (lane) >> 2;                                                \
        float v0 = __shfl(ac0, srcl);                                          \
        float v1 = __shfl(ac1, srcl);                                          \
        float v2 = __shfl(ac2, srcl);                                          \
        float v3 = __shfl(ac3, srcl);                                          \
        int jj = (lane) & 3;                                                   \
        accv = jj == 0 ? v0 : (jj == 1 ? v1 : (jj == 2 ? v2 : v3));            \
        accv += bf2f(Hh[(size_t)(wid) * 64 + (lane)]);                         \
    }

// LDS matvec epilogue: Ws[k*64+lane] layout, 2 lanes/bank (free), 4-way
// split accumulator chain.
#define LDS_MATVEC(hb, lane, Ws, o)                                            \
    float o;                                                                   \
    {                                                                          \
        float o0 = 0.f, o1 = 0.f, o2 = 0.f, o3 = 0.f;                          \
        _Pragma("unroll")                                                      \
        for (int k = 0; k < 64; k += 4) {                                      \
            o0 = fmaf(bcastf(hb, k),     Ws[(k)*64 + (lane)],     o0);         \
            o1 = fmaf(bcastf(hb, k + 1), Ws[(k+1)*64 + (lane)], o1);           \
            o2 = fmaf(bcastf(hb, k + 2), Ws[(k+2)*64 + (lane)], o2);           \
            o3 = fmaf(bcastf(hb, k + 3), Ws[(k+3)*64 + (lane)], o3);           \
        }                                                                      \
        o = (o0 + o1) + (o2 + o3);                                             \
    }

// ---------------------------------------------------------------------------
// aggA: h1 = leaky(dis*agg(Hs1) + b1); Hs2 = (h1 @ W2)*dis -> bf16
// ---------------------------------------------------------------------------
__global__ __launch_bounds__(256) void aggA_kernel(
    const unsigned short* __restrict__ Hh, const int* __restrict__ rpS,
    const int* __restrict__ rcnt, const int* __restrict__ ssrc,
    const float* __restrict__ dis, const float* __restrict__ b1,
    const float* __restrict__ W2, unsigned short* __restrict__ Oh, int n) {
    __shared__ float Ws[64 * 64];
    for (int i = threadIdx.x * 4; i < 4096; i += 256 * 4)
        *(float4*)&Ws[i] = *(const float4*)&W2[i];
    __syncthreads();

    int lane = threadIdx.x & 63;
    float bias = b1[lane];

    int wid = (int)((blockIdx.x * blockDim.x + threadIdx.x) >> 6);
    int nwaves = (int)((gridDim.x * blockDim.x) >> 6);
    for (; wid < n; wid += nwaves) {
        GATHER_WIDE(Hh, wid, lane, accv)
        float d = dis[wid];
        float h = fmaf(accv, d, bias);
        h = h > 0.f ? h : LEAKY_SLOPE * h;
        int hb = __builtin_bit_cast(int, h);
        LDS_MATVEC(hb, lane, Ws, o)
        Oh[(size_t)wid * 64 + lane] = f2bf(o * d);
    }
}

// ---------------------------------------------------------------------------
// aggB: h2 = leaky(dis*agg(Hs2) + b2); h2s = h2*dis -> bf16
// ---------------------------------------------------------------------------
__global__ __launch_bounds__(256) void aggB_kernel(
    const unsigned short* __restrict__ Hh, const int* __restrict__ rpS,
    const int* __restrict__ rcnt, const int* __restrict__ ssrc,
    const float* __restrict__ dis, const float* __restrict__ b2,
    unsigned short* __restrict__ Oh, int n) {
    int lane = threadIdx.x & 63;
    float bias = b2[lane];
    int wid = (int)((blockIdx.x * blockDim.x + threadIdx.x) >> 6);
    int nwaves = (int)((gridDim.x * blockDim.x) >> 6);
    for (; wid < n; wid += nwaves) {
        GATHER_WIDE(Hh, wid, lane, accv)
        float d = dis[wid];
        float h = fmaf(accv, d, bias);
        h = h > 0.f ? h : LEAKY_SLOPE * h;
        Oh[(size_t)wid * 64 + lane] = f2bf(h * d);
    }
}

// ---------------------------------------------------------------------------
// aggC: g = dis*agg(h2s); mu = g@Wmu + bmu; ls = g@Wls + bls -> d_out
// ---------------------------------------------------------------------------
__global__ __launch_bounds__(256) void aggC_kernel(
    const unsigned short* __restrict__ Hh, const int* __restrict__ rpS,
    const int* __restrict__ rcnt, const int* __restrict__ ssrc,
    const float* __restrict__ dis, const float* __restrict__ Wmu,
    const float* __restrict__ bmu, const float* __restrict__ Wls,
    const float* __restrict__ bls, float* __restrict__ mu,
    float* __restrict__ ls, int n) {
    __shared__ float Ws[64 * 64];
    for (int i = threadIdx.x; i < 4096; i += 256) {
        int k = i >> 6, c = i & 63;
        Ws[i] = (c < 32) ? Wmu[k * 32 + c] : Wls[k * 32 + (c - 32)];
    }
    __syncthreads();

    int lane = threadIdx.x & 63;
    int half = lane >> 5;
    int c = lane & 31;
    float bias = half ? bls[c] : bmu[c];
    float* outp = half ? ls : mu;

    int wid = (int)((blockIdx.x * blockDim.x + threadIdx.x) >> 6);
    int nwaves = (int)((gridDim.x * blockDim.x) >> 6);
    for (; wid < n; wid += nwaves) {
        GATHER_WIDE(Hh, wid, lane, accv)
        float gval = accv * dis[wid];
        int gb = __builtin_bit_cast(int, gval);
        LDS_MATVEC(gb, lane, Ws, o)
        outp[(size_t)wid * 32 + c] = o + bias;
    }
}

// ---------------------------------------------------------------------------
extern "C" void kernel_launch(void* const* d_in, const int* in_sizes, int n_in,
                              void* d_out, int out_size, void* d_ws, size_t ws_size,
                              hipStream_t stream) {
    const float* x   = (const float*)d_in[0];
    const int*   ei  = (const int*)d_in[1];
    const float* W1  = (const float*)d_in[2];
    const float* b1  = (const float*)d_in[3];
    const float* W2  = (const float*)d_in[4];
    const float* b2  = (const float*)d_in[5];
    const float* Wmu = (const float*)d_in[6];
    const float* bmu = (const float*)d_in[7];
    const float* Wls = (const float*)d_in[8];
    const float* bls = (const float*)d_in[9];

    const int N = in_sizes[0] / 128;   // 100000
    const int E = in_sizes[1] / 2;     // 1600000
    const int NCB = (N + CBSZ - 1) / CBSZ;   // 782 coarse buckets
    const int* src  = ei;
    const int* dstp = ei + E;

    auto align64 = [](size_t v) { return (v + 63) & ~(size_t)63; };
    char* ws = (char*)d_ws;
    float* dis    = (float*)ws; ws += align64((size_t)N * 4);
    int*   ccur16 = (int*)ws;   ws += align64((size_t)NCBMAX * 16 * 4);
    int*   rpS    = (int*)ws;   ws += align64((size_t)N * 4);
    int*   rcnt   = (int*)ws;   ws += align64((size_t)N * 4);
    unsigned* pairs = (unsigned*)ws; ws += align64((size_t)NCB * CAP * 4);
    int*   ssrc   = (int*)ws;   ws += align64((size_t)NCB * PADCAP * 4);
    unsigned short* bufH0 = (unsigned short*)ws; ws += align64(((size_t)N + 1) * 64 * 2);
    unsigned short* bufH1 = (unsigned short*)ws; ws += align64(((size_t)N + 1) * 64 * 2);

    float* mu = (float*)d_out;
    float* ls = mu + (size_t)N * 32;

    const int s1blocks = (E + CHUNK - 1) / CHUNK;   // 391

    // ---- counting sort into static 64B-aligned per-bucket padded CSR ----
    initcur_kernel<<<(NCB + 255) / 256, 256, 0, stream>>>(ccur16, NCB);
    scat1_kernel<<<s1blocks, 256, 0, stream>>>(src, dstp, ccur16, pairs, E);
    bucket_kernel<<<NCB, 256, 0, stream>>>(pairs, ccur16, dis, rpS, rcnt, ssrc, N);

    // ---- Hs1 = (x@W1)*dis (bf16); dummy row N zeroed inside (block 0) ----
    gemm1_kernel<<<N / 32, 256, 0, stream>>>(x, W1, dis, bufH0, bufH1, N);

    const int aggblocks = 2048;  // 8192 waves, grid-stride

    aggA_kernel<<<aggblocks, 256, 0, stream>>>(bufH0, rpS, rcnt, ssrc, dis, b1, W2, bufH1, N);
    aggB_kernel<<<aggblocks, 256, 0, stream>>>(bufH1, rpS, rcnt, ssrc, dis, b2, bufH0, N);
    aggC_kernel<<<aggblocks, 256, 0, stream>>>(bufH0, rpS, rcnt, ssrc, dis, Wmu, bmu,
                                               Wls, bls, mu, ls, N);
}